// Round 7
// baseline (353.880 us; speedup 1.0000x reference)
//
#include <hip/hip_runtime.h>
#include <math.h>

typedef _Float16 F16;
typedef __attribute__((ext_vector_type(8))) _Float16 f16x8;
typedef __attribute__((ext_vector_type(4))) float f32x4;

// ---------------------------------------------------------------- convert f32 -> f16
__global__ __launch_bounds__(256) void cvt_kernel(const float* __restrict__ src,
                                                  F16* __restrict__ dst, int n4) {
  int i = blockIdx.x * 256 + threadIdx.x;
  if (i >= n4) return;
  float4 v = reinterpret_cast<const float4*>(src)[i];
  union { F16 h[4]; uint2 u; } pk;
  pk.h[0] = (F16)v.x; pk.h[1] = (F16)v.y; pk.h[2] = (F16)v.z; pk.h[3] = (F16)v.w;
  reinterpret_cast<uint2*>(dst)[i] = pk.u;
}

// zero Kt[b][h][1023][64..127] (rel-shift trailing zero row)
__global__ void fill_kernel(F16* __restrict__ Kt) {
  int id = blockIdx.x * 256 + threadIdx.x;  // 0..4095
  int b = id >> 10, h = (id >> 6) & 15, d = id & 63;
  Kt[(((size_t)(b * 16 + h)) * 1024 + 1023) * 128 + 64 + d] = (F16)0.f;
}

// ---------------------------------------------------------------- GEMM C = A @ W^T
// A: [M,1024] f16 row-major; W: [1024,1024] f16 row-major (out,in)
// MODE 0=Q-pack 1=K-pack 2=V-pack(transposed) 3=R-pack(shifted,bcast b) 4=Out(+residual f32)
template <int MODE>
__global__ __launch_bounds__(256) void gemm_bt(const F16* __restrict__ A,
                                               const F16* __restrict__ W,
                                               const float* __restrict__ bias1,
                                               const float* __restrict__ bias2,
                                               F16* __restrict__ outp,
                                               float* __restrict__ outf,
                                               const float* __restrict__ addsrc) {
  const int tid = threadIdx.x;
  const int lane = tid & 63, wid = tid >> 6;
  const int wm = wid >> 1, wn = wid & 1;
  const int l15 = lane & 15, g = lane >> 4, hi8 = g * 8;
  const int m0 = blockIdx.x * 128, n0 = blockIdx.y * 128;

  __shared__ __align__(16) F16 As[128][72];
  __shared__ __align__(16) F16 Bs[128][72];

  f32x4 acc[4][4] = {};

  for (int k0 = 0; k0 < 1024; k0 += 64) {
#pragma unroll
    for (int j = 0; j < 4; ++j) {
      int chunk = tid + j * 256;
      int r = chunk >> 3, cc = (chunk & 7) * 8;
      *(uint4*)&As[r][cc] = *(const uint4*)&A[(size_t)(m0 + r) * 1024 + k0 + cc];
      *(uint4*)&Bs[r][cc] = *(const uint4*)&W[(size_t)(n0 + r) * 1024 + k0 + cc];
    }
    __syncthreads();
#pragma unroll
    for (int kk = 0; kk < 2; ++kk) {
      f16x8 a[4], b[4];
#pragma unroll
      for (int m = 0; m < 4; ++m) a[m] = *(const f16x8*)&As[wm * 64 + m * 16 + l15][kk * 32 + hi8];
#pragma unroll
      for (int n = 0; n < 4; ++n) b[n] = *(const f16x8*)&Bs[wn * 64 + n * 16 + l15][kk * 32 + hi8];
#pragma unroll
      for (int m = 0; m < 4; ++m)
#pragma unroll
        for (int n = 0; n < 4; ++n)
          acc[m][n] = __builtin_amdgcn_mfma_f32_16x16x32_f16(a[m], b[n], acc[m][n], 0, 0, 0);
    }
    __syncthreads();
  }

#pragma unroll
  for (int m = 0; m < 4; ++m)
#pragma unroll
    for (int n = 0; n < 4; ++n)
#pragma unroll
      for (int i = 0; i < 4; ++i) {
        int row = m0 + wm * 64 + m * 16 + g * 4 + i;
        int col = n0 + wn * 64 + n * 16 + l15;
        float v = acc[m][n][i];
        if (MODE == 0) {  // Q~ : [(q+rwb)*s ; (q+rrb)*s]
          int b = row >> 10, q = row & 1023, h = col >> 6, d = col & 63;
          size_t base = (((size_t)(b * 16 + h)) * 1024 + q) * 128;
          outp[base + d]      = (F16)((v + bias1[col]) * 0.125f);
          outp[base + 64 + d] = (F16)((v + bias2[col]) * 0.125f);
        } else if (MODE == 1) {  // K half of K~
          int b = row >> 10, q = row & 1023, h = col >> 6, d = col & 63;
          outp[(((size_t)(b * 16 + h)) * 1024 + q) * 128 + d] = (F16)v;
        } else if (MODE == 2) {  // V transposed: Vt[b,h,d,k]
          int b = row >> 10, q = row & 1023, h = col >> 6, d = col & 63;
          outp[(((size_t)(b * 16 + h)) * 64 + d) * 1024 + q] = (F16)v;
        } else if (MODE == 3) {  // rel-shifted R half of K~, broadcast over b
          if (row > 0) {
            int h = col >> 6, d = col & 63;
#pragma unroll
            for (int b2 = 0; b2 < 4; ++b2)
              outp[(((size_t)(b2 * 16 + h)) * 1024 + (row - 1)) * 128 + 64 + d] = (F16)v;
          }
        } else {  // output proj + residual
          outf[(size_t)row * 1024 + col] = v + addsrc[(size_t)row * 1024 + col];
        }
      }
}

// ---------------------------------------------------------------- flash attention
// Qt/Kt: [B,H,1024,128] f16; Vt: [B,H,64,1024] f16; av: [4096,1024] f16
__global__ __launch_bounds__(256) void attn_kernel(const F16* __restrict__ Qt,
                                                   const F16* __restrict__ Kt,
                                                   const F16* __restrict__ Vt,
                                                   F16* __restrict__ av) {
  const int qb = blockIdx.x, h = blockIdx.y, b = blockIdx.z;
  const int tid = threadIdx.x, lane = tid & 63, w = tid >> 6;
  const int l15 = lane & 15, g = lane >> 4, hi8 = g * 8;
  const size_t bh = (size_t)(b * 16 + h);
  const F16* Qb = Qt + bh * 1024 * 128;
  const F16* Kb = Kt + bh * 1024 * 128;
  const F16* Vb = Vt + bh * 64 * 1024;

  __shared__ __align__(16) F16 Ks[64][136];
  __shared__ __align__(16) F16 Vs[64][72];
  __shared__ __align__(16) F16 Ps[4][16][72];

  f16x8 qf[4];
  const int qrow = qb * 64 + w * 16 + l15;
#pragma unroll
  for (int t = 0; t < 4; ++t)
    qf[t] = *(const f16x8*)&Qb[(size_t)qrow * 128 + t * 32 + hi8];

  f32x4 accO[4] = {};
  float mi[4], li[4];
#pragma unroll
  for (int i = 0; i < 4; ++i) { mi[i] = -INFINITY; li[i] = 0.f; }

  for (int kt = 0; kt <= qb; ++kt) {
#pragma unroll
    for (int j = 0; j < 4; ++j) {  // K~ tile 64x128
      int chunk = tid + j * 256;
      int r = chunk >> 4, cc = (chunk & 15) * 8;
      *(uint4*)&Ks[r][cc] = *(const uint4*)&Kb[(size_t)(kt * 64 + r) * 128 + cc];
    }
#pragma unroll
    for (int j = 0; j < 2; ++j) {  // V tile 64(dh) x 64(k)
      int chunk = tid + j * 256;
      int r = chunk >> 3, cc = (chunk & 7) * 8;
      *(uint4*)&Vs[r][cc] = *(const uint4*)&Vb[(size_t)r * 1024 + kt * 64 + cc];
    }
    __syncthreads();

    f32x4 s[4] = {};
#pragma unroll
    for (int st = 0; st < 4; ++st)
#pragma unroll
      for (int t = 0; t < 4; ++t) {
        f16x8 kf = *(const f16x8*)&Ks[st * 16 + l15][t * 32 + hi8];
        s[st] = __builtin_amdgcn_mfma_f32_16x16x32_f16(qf[t], kf, s[st], 0, 0, 0);
      }

    if (kt == qb) {  // diagonal tile: causal mask
#pragma unroll
      for (int st = 0; st < 4; ++st)
#pragma unroll
        for (int i = 0; i < 4; ++i) {
          int row = qb * 64 + w * 16 + g * 4 + i;
          int col = kt * 64 + st * 16 + l15;
          if (col > row) s[st][i] = -1e30f;
        }
    }

#pragma unroll
    for (int i = 0; i < 4; ++i) {
      float v = fmaxf(fmaxf(s[0][i], s[1][i]), fmaxf(s[2][i], s[3][i]));
      v = fmaxf(v, __shfl_xor(v, 1));
      v = fmaxf(v, __shfl_xor(v, 2));
      v = fmaxf(v, __shfl_xor(v, 4));
      v = fmaxf(v, __shfl_xor(v, 8));
      float mnew = fmaxf(mi[i], v);
      float sum = 0.f;
#pragma unroll
      for (int st = 0; st < 4; ++st) {
        float p = __expf(s[st][i] - mnew);
        sum += p;
        Ps[w][g * 4 + i][st * 16 + l15] = (F16)p;
      }
      sum += __shfl_xor(sum, 1);
      sum += __shfl_xor(sum, 2);
      sum += __shfl_xor(sum, 4);
      sum += __shfl_xor(sum, 8);
      float alpha = __expf(mi[i] - mnew);
      li[i] = li[i] * alpha + sum;
      mi[i] = mnew;
#pragma unroll
      for (int n = 0; n < 4; ++n) accO[n][i] *= alpha;
    }

#pragma unroll
    for (int t2 = 0; t2 < 2; ++t2) {
      f16x8 pa = *(const f16x8*)&Ps[w][l15][t2 * 32 + hi8];
#pragma unroll
      for (int n = 0; n < 4; ++n) {
        f16x8 vb = *(const f16x8*)&Vs[n * 16 + l15][t2 * 32 + hi8];
        accO[n] = __builtin_amdgcn_mfma_f32_16x16x32_f16(pa, vb, accO[n], 0, 0, 0);
      }
    }
    __syncthreads();
  }

#pragma unroll
  for (int n = 0; n < 4; ++n)
#pragma unroll
    for (int i = 0; i < 4; ++i) {
      int row = qb * 64 + w * 16 + g * 4 + i;
      av[((size_t)b * 1024 + row) * 1024 + h * 64 + n * 16 + l15] =
          (F16)(accO[n][i] / li[i]);
    }
}

// ---------------------------------------------------------------- layernorm
__global__ __launch_bounds__(256) void ln_kernel(const float* __restrict__ x,
                                                 const float* __restrict__ gamma,
                                                 const float* __restrict__ beta,
                                                 float* __restrict__ out) {
  const int row = blockIdx.x;
  const int t = threadIdx.x;
  const float* xr = x + (size_t)row * 1024;
  float4 v = reinterpret_cast<const float4*>(xr)[t];
  float s = v.x + v.y + v.z + v.w;
  float s2 = v.x * v.x + v.y * v.y + v.z * v.z + v.w * v.w;
  for (int off = 32; off; off >>= 1) {
    s += __shfl_down(s, off);
    s2 += __shfl_down(s2, off);
  }
  __shared__ float ps[4], ps2[4];
  int wid = t >> 6, ln = t & 63;
  if (ln == 0) { ps[wid] = s; ps2[wid] = s2; }
  __syncthreads();
  if (t == 0) {
    float a = 0, c = 0;
    for (int i = 0; i < 4; ++i) { a += ps[i]; c += ps2[i]; }
    ps[0] = a; ps2[0] = c;
  }
  __syncthreads();
  float mean = ps[0] * (1.f / 1024.f);
  float var = ps2[0] * (1.f / 1024.f) - mean * mean;
  float rstd = rsqrtf(var + 1e-5f);
  float4 gm = reinterpret_cast<const float4*>(gamma)[t];
  float4 bt = reinterpret_cast<const float4*>(beta)[t];
  float4 o;
  o.x = (v.x - mean) * rstd * gm.x + bt.x;
  o.y = (v.y - mean) * rstd * gm.y + bt.y;
  o.z = (v.z - mean) * rstd * gm.z + bt.z;
  o.w = (v.w - mean) * rstd * gm.w + bt.w;
  reinterpret_cast<float4*>(out + (size_t)row * 1024)[t] = o;
}

// ---------------------------------------------------------------- launch
extern "C" void kernel_launch(void* const* d_in, const int* in_sizes, int n_in,
                              void* d_out, int out_size, void* d_ws, size_t ws_size,
                              hipStream_t stream) {
  const float* w = (const float*)d_in[0];
  const float* r = (const float*)d_in[1];
  const float* rwb = (const float*)d_in[2];
  const float* rrb = (const float*)d_in[3];
  const float* Wq = (const float*)d_in[5];
  const float* Wk = (const float*)d_in[6];
  const float* Wv = (const float*)d_in[7];
  const float* Wr = (const float*)d_in[8];
  const float* Wo = (const float*)d_in[9];
  const float* gamma = (const float*)d_in[10];
  const float* beta = (const float*)d_in[11];
  float* out = (float*)d_out;

  char* ws = (char*)d_ws;
  size_t off = 0;
  F16* w_bf = (F16*)(ws + off); off += (size_t)4096 * 1024 * 2;
  F16* r_bf = (F16*)(ws + off); off += (size_t)1024 * 1024 * 2;
  F16* wq_bf = (F16*)(ws + off); off += (size_t)1024 * 1024 * 2;
  F16* wk_bf = (F16*)(ws + off); off += (size_t)1024 * 1024 * 2;
  F16* wv_bf = (F16*)(ws + off); off += (size_t)1024 * 1024 * 2;
  F16* wr_bf = (F16*)(ws + off); off += (size_t)1024 * 1024 * 2;
  F16* wo_bf = (F16*)(ws + off); off += (size_t)1024 * 1024 * 2;
  F16* Qt = (F16*)(ws + off); off += (size_t)4 * 16 * 1024 * 128 * 2;
  F16* Kt = (F16*)(ws + off); off += (size_t)4 * 16 * 1024 * 128 * 2;
  F16* Vt = (F16*)(ws + off); off += (size_t)4 * 16 * 64 * 1024 * 2;
  F16* av = (F16*)(ws + off); off += (size_t)4096 * 1024 * 2;
  float* tmp = (float*)(ws + off); off += (size_t)4096 * 1024 * 4;

  cvt_kernel<<<4096, 256, 0, stream>>>(w, w_bf, 1048576);
  cvt_kernel<<<1024, 256, 0, stream>>>(r, r_bf, 262144);
  cvt_kernel<<<1024, 256, 0, stream>>>(Wq, wq_bf, 262144);
  cvt_kernel<<<1024, 256, 0, stream>>>(Wk, wk_bf, 262144);
  cvt_kernel<<<1024, 256, 0, stream>>>(Wv, wv_bf, 262144);
  cvt_kernel<<<1024, 256, 0, stream>>>(Wr, wr_bf, 262144);
  cvt_kernel<<<1024, 256, 0, stream>>>(Wo, wo_bf, 262144);
  fill_kernel<<<16, 256, 0, stream>>>(Kt);

  gemm_bt<0><<<dim3(32, 8), 256, 0, stream>>>(w_bf, wq_bf, rwb, rrb, Qt, nullptr, nullptr);
  gemm_bt<1><<<dim3(32, 8), 256, 0, stream>>>(w_bf, wk_bf, nullptr, nullptr, Kt, nullptr, nullptr);
  gemm_bt<2><<<dim3(32, 8), 256, 0, stream>>>(w_bf, wv_bf, nullptr, nullptr, Vt, nullptr, nullptr);
  gemm_bt<3><<<dim3(8, 8), 256, 0, stream>>>(r_bf, wr_bf, nullptr, nullptr, Kt, nullptr, nullptr);

  attn_kernel<<<dim3(16, 16, 4), 256, 0, stream>>>(Qt, Kt, Vt, av);

  gemm_bt<4><<<dim3(32, 8), 256, 0, stream>>>(av, wo_bf, nullptr, nullptr, nullptr, tmp, w);
  ln_kernel<<<4096, 256, 0, stream>>>(tmp, gamma, beta, out);
}

// Round 11
// 308.828 us; speedup vs baseline: 1.1459x; 1.1459x over previous
//
#include <hip/hip_runtime.h>
#include <math.h>

typedef _Float16 F16;
typedef __attribute__((ext_vector_type(8))) _Float16 f16x8;
typedef __attribute__((ext_vector_type(4))) float f32x4;

// ---------------------------------------------------------------- convert f32 -> f16
__global__ __launch_bounds__(256) void cvt_kernel(const float* __restrict__ src,
                                                  F16* __restrict__ dst, int n4) {
  int i = blockIdx.x * 256 + threadIdx.x;
  if (i >= n4) return;
  float4 v = reinterpret_cast<const float4*>(src)[i];
  union { F16 h[4]; uint2 u; } pk;
  pk.h[0] = (F16)v.x; pk.h[1] = (F16)v.y; pk.h[2] = (F16)v.z; pk.h[3] = (F16)v.w;
  reinterpret_cast<uint2*>(dst)[i] = pk.u;
}

// zero Kt[b][h][1023][64..127] (rel-shift trailing zero row)
__global__ void fill_kernel(F16* __restrict__ Kt) {
  int id = blockIdx.x * 256 + threadIdx.x;  // 0..4095
  int b = id >> 10, h = (id >> 6) & 15, d = id & 63;
  Kt[(((size_t)(b * 16 + h)) * 1024 + 1023) * 128 + 64 + d] = (F16)0.f;
}

// ---------------------------------------------------------------- GEMM C = A @ W^T
// MODE 0: fused QKV (W = [3072,1024], grid.y=24). which=col>>10: 0=Q-pack 1=K-pack 2=V-pack
// MODE 3: R-pack (shifted, bcast b). MODE 4: out-proj + residual (f32)
template <int MODE>
__global__ __launch_bounds__(256) void gemm_bt(const F16* __restrict__ A,
                                               const F16* __restrict__ W,
                                               const float* __restrict__ bias1,
                                               const float* __restrict__ bias2,
                                               F16* __restrict__ outq,
                                               F16* __restrict__ outk,
                                               F16* __restrict__ outv,
                                               float* __restrict__ outf,
                                               const float* __restrict__ addsrc) {
  const int tid = threadIdx.x;
  const int lane = tid & 63, wid = tid >> 6;
  const int wm = wid >> 1, wn = wid & 1;
  const int l15 = lane & 15, g = lane >> 4, hi8 = g * 8;
  const int m0 = blockIdx.x * 128, n0 = blockIdx.y * 128;

  __shared__ __align__(16) F16 As[128][72];
  __shared__ __align__(16) F16 Bs[128][72];

  f32x4 acc[4][4] = {};

  for (int k0 = 0; k0 < 1024; k0 += 64) {
#pragma unroll
    for (int j = 0; j < 4; ++j) {
      int chunk = tid + j * 256;
      int r = chunk >> 3, cc = (chunk & 7) * 8;
      *(uint4*)&As[r][cc] = *(const uint4*)&A[(size_t)(m0 + r) * 1024 + k0 + cc];
      *(uint4*)&Bs[r][cc] = *(const uint4*)&W[(size_t)(n0 + r) * 1024 + k0 + cc];
    }
    __syncthreads();
#pragma unroll
    for (int kk = 0; kk < 2; ++kk) {
      f16x8 a[4], b[4];
#pragma unroll
      for (int m = 0; m < 4; ++m) a[m] = *(const f16x8*)&As[wm * 64 + m * 16 + l15][kk * 32 + hi8];
#pragma unroll
      for (int n = 0; n < 4; ++n) b[n] = *(const f16x8*)&Bs[wn * 64 + n * 16 + l15][kk * 32 + hi8];
#pragma unroll
      for (int m = 0; m < 4; ++m)
#pragma unroll
        for (int n = 0; n < 4; ++n)
          acc[m][n] = __builtin_amdgcn_mfma_f32_16x16x32_f16(a[m], b[n], acc[m][n], 0, 0, 0);
    }
    __syncthreads();
  }

#pragma unroll
  for (int m = 0; m < 4; ++m)
#pragma unroll
    for (int n = 0; n < 4; ++n)
#pragma unroll
      for (int i = 0; i < 4; ++i) {
        int row = m0 + wm * 64 + m * 16 + g * 4 + i;
        int col = n0 + wn * 64 + n * 16 + l15;
        float v = acc[m][n][i];
        if (MODE == 0) {  // fused QKV epilogue
          int which = col >> 10, c = col & 1023;
          int hh = c >> 6, d = c & 63;
          int bb = row >> 10, q = row & 1023;
          if (which == 0) {       // Q~ : [(q+rwb)*s ; (q+rrb)*s]
            size_t base = (((size_t)(bb * 16 + hh)) * 1024 + q) * 128;
            outq[base + d]      = (F16)((v + bias1[c]) * 0.125f);
            outq[base + 64 + d] = (F16)((v + bias2[c]) * 0.125f);
          } else if (which == 1) { // K half of K~
            outk[(((size_t)(bb * 16 + hh)) * 1024 + q) * 128 + d] = (F16)v;
          } else {                 // V transposed: Vt[b,h,d,k]
            outv[(((size_t)(bb * 16 + hh)) * 64 + d) * 1024 + q] = (F16)v;
          }
        } else if (MODE == 3) {  // rel-shifted R half of K~, broadcast over b
          if (row > 0) {
            int hh = col >> 6, d = col & 63;
#pragma unroll
            for (int b2 = 0; b2 < 4; ++b2)
              outk[(((size_t)(b2 * 16 + hh)) * 1024 + (row - 1)) * 128 + 64 + d] = (F16)v;
          }
        } else {  // output proj + residual
          outf[(size_t)row * 1024 + col] = v + addsrc[(size_t)row * 1024 + col];
        }
      }
}

// ---------------------------------------------------------------- flash attention
// Qt/Kt: [B,H,1024,128] f16; Vt: [B,H,64,1024] f16; av: [4096,1024] f16
// Block handles q-tiles qpair and 15-qpair (uniform 17 KV-iterations).
// Double-buffered K/V staging with async prefetch; XOR-swizzled LDS.
__global__ __launch_bounds__(256) void attn_kernel(const F16* __restrict__ Qt,
                                                   const F16* __restrict__ Kt,
                                                   const F16* __restrict__ Vt,
                                                   F16* __restrict__ av) {
  const int qpair = blockIdx.x, h = blockIdx.y, b = blockIdx.z;
  const int tid = threadIdx.x, lane = tid & 63, w = tid >> 6;
  const int l15 = lane & 15, g = lane >> 4, hi8 = g * 8;
  const size_t bh = (size_t)(b * 16 + h);
  const F16* Qb = Qt + bh * 1024 * 128;
  const F16* Kb = Kt + bh * 1024 * 128;
  const F16* Vb = Vt + bh * 64 * 1024;
  const int qt0 = qpair, qt1 = 15 - qpair;
  const int nit = qt0 + qt1 + 2;  // 17

  __shared__ __align__(16) F16 Ks[2][64][128];  // swizzled c16 ^= r&7
  __shared__ __align__(16) F16 Vs[2][64][64];   // swizzled
  __shared__ __align__(16) F16 Ps[4][16][72];

  const int kr0 = tid >> 4, kc0 = tid & 15;  // K staging: rows kr0+j*16, 16B-chunk kc0
  const int vr0 = tid >> 3, vc0 = tid & 7;   // V staging: rows vr0+j*32, chunk vc0

  uint4 kreg[4], vreg[2];

  auto kt_of = [&](int it) { return it <= qt0 ? it : it - qt0 - 1; };

  auto load_regs = [&](int it) {
    int kt = kt_of(it);
#pragma unroll
    for (int j = 0; j < 4; ++j)
      kreg[j] = *(const uint4*)&Kb[(size_t)(kt * 64 + kr0 + j * 16) * 128 + kc0 * 8];
#pragma unroll
    for (int j = 0; j < 2; ++j)
      vreg[j] = *(const uint4*)&Vb[(size_t)(vr0 + j * 32) * 1024 + kt * 64 + vc0 * 8];
  };
  auto write_regs = [&](int buf) {
#pragma unroll
    for (int j = 0; j < 4; ++j) {
      int r = kr0 + j * 16;
      *(uint4*)&Ks[buf][r][(kc0 ^ (r & 7)) * 8] = kreg[j];
    }
#pragma unroll
    for (int j = 0; j < 2; ++j) {
      int r = vr0 + j * 32;
      *(uint4*)&Vs[buf][r][(vc0 ^ (r & 7)) * 8] = vreg[j];
    }
  };

  int qtile = qt0;
  int qrow = qtile * 64 + w * 16 + l15;
  f16x8 qf[4];
#pragma unroll
  for (int t = 0; t < 4; ++t) qf[t] = *(const f16x8*)&Qb[(size_t)qrow * 128 + t * 32 + hi8];

  f32x4 accO[4] = {};
  float mi[4], li[4];
#pragma unroll
  for (int i = 0; i < 4; ++i) { mi[i] = -INFINITY; li[i] = 0.f; }

  load_regs(0);
  write_regs(0);
  __syncthreads();

  for (int it = 0; it < nit; ++it) {
    const int buf = it & 1;
    const int kt = kt_of(it);
    if (it + 1 < nit) load_regs(it + 1);  // async: in flight across compute

    // QK~^T
    f32x4 s[4] = {};
#pragma unroll
    for (int st = 0; st < 4; ++st) {
      const int krow = st * 16 + l15, swz = krow & 7;
#pragma unroll
      for (int t = 0; t < 4; ++t) {
        f16x8 kf = *(const f16x8*)&Ks[buf][krow][((t * 4 + g) ^ swz) * 8];
        s[st] = __builtin_amdgcn_mfma_f32_16x16x32_f16(qf[t], kf, s[st], 0, 0, 0);
      }
    }

    if (kt == qtile) {  // diagonal tile: causal mask (local coords suffice)
#pragma unroll
      for (int st = 0; st < 4; ++st)
#pragma unroll
        for (int i = 0; i < 4; ++i)
          if (st * 16 + l15 > w * 16 + g * 4 + i) s[st][i] = -1e30f;
    }

    // online softmax
#pragma unroll
    for (int i = 0; i < 4; ++i) {
      float v = fmaxf(fmaxf(s[0][i], s[1][i]), fmaxf(s[2][i], s[3][i]));
      v = fmaxf(v, __shfl_xor(v, 1));
      v = fmaxf(v, __shfl_xor(v, 2));
      v = fmaxf(v, __shfl_xor(v, 4));
      v = fmaxf(v, __shfl_xor(v, 8));
      float mnew = fmaxf(mi[i], v);
      float sum = 0.f;
#pragma unroll
      for (int st = 0; st < 4; ++st) {
        float p = __expf(s[st][i] - mnew);
        sum += p;
        Ps[w][g * 4 + i][st * 16 + l15] = (F16)p;
      }
      sum += __shfl_xor(sum, 1);
      sum += __shfl_xor(sum, 2);
      sum += __shfl_xor(sum, 4);
      sum += __shfl_xor(sum, 8);
      float alpha = __expf(mi[i] - mnew);
      li[i] = li[i] * alpha + sum;
      mi[i] = mnew;
#pragma unroll
      for (int n = 0; n < 4; ++n) accO[n][i] *= alpha;
    }

    // PV
#pragma unroll
    for (int t2 = 0; t2 < 2; ++t2) {
      f16x8 pa = *(const f16x8*)&Ps[w][l15][t2 * 32 + hi8];
#pragma unroll
      for (int n = 0; n < 4; ++n) {
        const int vrow = n * 16 + l15;
        f16x8 vb = *(const f16x8*)&Vs[buf][vrow][((t2 * 4 + g) ^ (vrow & 7)) * 8];
        accO[n] = __builtin_amdgcn_mfma_f32_16x16x32_f16(pa, vb, accO[n], 0, 0, 0);
      }
    }

    if (kt == qtile) {  // phase finished: emit this q-tile, reset for next
#pragma unroll
      for (int n = 0; n < 4; ++n)
#pragma unroll
        for (int i = 0; i < 4; ++i) {
          int row = qtile * 64 + w * 16 + g * 4 + i;
          av[((size_t)b * 1024 + row) * 1024 + h * 64 + n * 16 + l15] =
              (F16)(accO[n][i] / li[i]);
        }
      if (it + 1 < nit) {
        qtile = qt1;
        qrow = qtile * 64 + w * 16 + l15;
#pragma unroll
        for (int t = 0; t < 4; ++t)
          qf[t] = *(const f16x8*)&Qb[(size_t)qrow * 128 + t * 32 + hi8];
#pragma unroll
        for (int i = 0; i < 4; ++i) { mi[i] = -INFINITY; li[i] = 0.f; }
#pragma unroll
        for (int n = 0; n < 4; ++n) accO[n] = f32x4{0.f, 0.f, 0.f, 0.f};
      }
    }

    __syncthreads();
    if (it + 1 < nit) write_regs(buf ^ 1);
    __syncthreads();
  }
}

// ---------------------------------------------------------------- layernorm
__global__ __launch_bounds__(256) void ln_kernel(const float* __restrict__ x,
                                                 const float* __restrict__ gamma,
                                                 const float* __restrict__ beta,
                                                 float* __restrict__ out) {
  const int row = blockIdx.x;
  const int t = threadIdx.x;
  const float* xr = x + (size_t)row * 1024;
  float4 v = reinterpret_cast<const float4*>(xr)[t];
  float s = v.x + v.y + v.z + v.w;
  float s2 = v.x * v.x + v.y * v.y + v.z * v.z + v.w * v.w;
  for (int off = 32; off; off >>= 1) {
    s += __shfl_down(s, off);
    s2 += __shfl_down(s2, off);
  }
  __shared__ float ps[4], ps2[4];
  int wid = t >> 6, ln = t & 63;
  if (ln == 0) { ps[wid] = s; ps2[wid] = s2; }
  __syncthreads();
  if (t == 0) {
    float a = 0, c = 0;
    for (int i = 0; i < 4; ++i) { a += ps[i]; c += ps2[i]; }
    ps[0] = a; ps2[0] = c;
  }
  __syncthreads();
  float mean = ps[0] * (1.f / 1024.f);
  float var = ps2[0] * (1.f / 1024.f) - mean * mean;
  float rstd = rsqrtf(var + 1e-5f);
  float4 gm = reinterpret_cast<const float4*>(gamma)[t];
  float4 bt = reinterpret_cast<const float4*>(beta)[t];
  float4 o;
  o.x = (v.x - mean) * rstd * gm.x + bt.x;
  o.y = (v.y - mean) * rstd * gm.y + bt.y;
  o.z = (v.z - mean) * rstd * gm.z + bt.z;
  o.w = (v.w - mean) * rstd * gm.w + bt.w;
  reinterpret_cast<float4*>(out + (size_t)row * 1024)[t] = o;
}

// ---------------------------------------------------------------- launch
extern "C" void kernel_launch(void* const* d_in, const int* in_sizes, int n_in,
                              void* d_out, int out_size, void* d_ws, size_t ws_size,
                              hipStream_t stream) {
  const float* w = (const float*)d_in[0];
  const float* r = (const float*)d_in[1];
  const float* rwb = (const float*)d_in[2];
  const float* rrb = (const float*)d_in[3];
  const float* Wq = (const float*)d_in[5];
  const float* Wk = (const float*)d_in[6];
  const float* Wv = (const float*)d_in[7];
  const float* Wr = (const float*)d_in[8];
  const float* Wo = (const float*)d_in[9];
  const float* gamma = (const float*)d_in[10];
  const float* beta = (const float*)d_in[11];
  float* out = (float*)d_out;

  char* ws = (char*)d_ws;
  size_t off = 0;
  F16* w_f = (F16*)(ws + off); off += (size_t)4096 * 1024 * 2;
  F16* r_f = (F16*)(ws + off); off += (size_t)1024 * 1024 * 2;
  F16* wqkv_f = (F16*)(ws + off); off += (size_t)3 * 1024 * 1024 * 2;
  F16* wr_f = (F16*)(ws + off); off += (size_t)1024 * 1024 * 2;
  F16* wo_f = (F16*)(ws + off); off += (size_t)1024 * 1024 * 2;
  F16* Qt = (F16*)(ws + off); off += (size_t)4 * 16 * 1024 * 128 * 2;
  F16* Kt = (F16*)(ws + off); off += (size_t)4 * 16 * 1024 * 128 * 2;
  F16* Vt = (F16*)(ws + off); off += (size_t)4 * 16 * 64 * 1024 * 2;
  F16* av = (F16*)(ws + off); off += (size_t)4096 * 1024 * 2;
  float* tmp = (float*)(ws + off); off += (size_t)4096 * 1024 * 4;

  cvt_kernel<<<4096, 256, 0, stream>>>(w, w_f, 1048576);
  cvt_kernel<<<1024, 256, 0, stream>>>(r, r_f, 262144);
  cvt_kernel<<<1024, 256, 0, stream>>>(Wq, wqkv_f, 262144);
  cvt_kernel<<<1024, 256, 0, stream>>>(Wk, wqkv_f + (size_t)1024 * 1024, 262144);
  cvt_kernel<<<1024, 256, 0, stream>>>(Wv, wqkv_f + (size_t)2 * 1024 * 1024, 262144);
  cvt_kernel<<<1024, 256, 0, stream>>>(Wr, wr_f, 262144);
  cvt_kernel<<<1024, 256, 0, stream>>>(Wo, wo_f, 262144);
  fill_kernel<<<16, 256, 0, stream>>>(Kt);

  // fused QKV projection
  gemm_bt<0><<<dim3(32, 24), 256, 0, stream>>>(w_f, wqkv_f, rwb, rrb, Qt, Kt, Vt, nullptr, nullptr);
  // R projection (rel-shifted into Kt R-half)
  gemm_bt<3><<<dim3(8, 8), 256, 0, stream>>>(r_f, wr_f, nullptr, nullptr, nullptr, Kt, nullptr, nullptr, nullptr);

  attn_kernel<<<dim3(8, 16, 4), 256, 0, stream>>>(Qt, Kt, Vt, av);

  // output projection + residual
  gemm_bt<4><<<dim3(32, 8), 256, 0, stream>>>(av, wo_f, nullptr, nullptr, nullptr, nullptr, nullptr, tmp, w);
  ln_kernel<<<4096, 256, 0, stream>>>(tmp, gamma, beta, out);
}